// Round 1
// baseline (230.301 us; speedup 1.0000x reference)
//
#include <hip/hip_runtime.h>
#include <hip/hip_bf16.h>

#define HID 128
#define LDW 136   // padded LDS row stride (bf16 elems): 272B rows, 16B-aligned, bank-spread

typedef __attribute__((ext_vector_type(8))) __bf16 bf16x8;
typedef __attribute__((ext_vector_type(4))) float f32x4;
typedef __attribute__((ext_vector_type(4))) unsigned short us4;

__device__ __forceinline__ unsigned short f2bf(float f){
  unsigned int u = __float_as_uint(f);
  unsigned int r = (u + 0x7FFFu + ((u >> 16) & 1u)) >> 16;  // RNE
  return (unsigned short)r;
}

// ---- scatter side: build per-dst edge lists (no fp32 atomics) ----

__global__ void count_kernel(const int* __restrict__ ei, int* __restrict__ cnt, int E){
  int e = blockIdx.x*256 + threadIdx.x;
  if (e < E) atomicAdd(&cnt[ei[E + e]], 1);
}

__global__ void offsets_kernel(const int* __restrict__ cnt, int* __restrict__ off,
                               int* __restrict__ gcur, int N){
  int n = blockIdx.x*256 + threadIdx.x;
  int lane = threadIdx.x & 63;
  int c = (n < N) ? cnt[n] : 0;
  int incl = c;
  #pragma unroll
  for (int s = 1; s < 64; s <<= 1){
    int u = __shfl_up(incl, s);
    if (lane >= s) incl += u;
  }
  int total = __shfl(incl, 63);
  int base = 0;
  if (lane == 63) base = atomicAdd(gcur, total);
  base = __shfl(base, 63);
  if (n < N) off[n] = base + incl - c;
}

__global__ void fill_kernel(const int* __restrict__ ei, const int* __restrict__ off,
                            int* __restrict__ cur, int* __restrict__ elist, int E){
  int e = blockIdx.x*256 + threadIdx.x;
  if (e >= E) return;
  int s = ei[e], d = ei[E + e];
  int slot = off[d] + atomicAdd(&cur[d], 1);
  elist[slot] = s;
}

// one wave per node: sum incoming X rows, divide by deg, write agg (f32)
__global__ void gather_kernel(const float* __restrict__ X, const int* __restrict__ elist,
                              const int* __restrict__ off, const int* __restrict__ cnt,
                              float* __restrict__ agg, int N){
  int wv = threadIdx.x >> 6, lane = threadIdx.x & 63;
  int n = blockIdx.x*4 + wv;
  if (n >= N) return;
  int base = off[n], d = cnt[n];
  float ax = 0.f, ay = 0.f;
  const float2* Xp = (const float2*)X;
  for (int j = 0; j < d; ++j){
    int s = elist[base + j];
    float2 v = Xp[(size_t)s*64 + lane];
    ax += v.x; ay += v.y;
  }
  float inv = (d > 0) ? 1.f/(float)d : 0.f;  // deg clipped to >=1; d==0 -> agg 0
  float2 o; o.x = ax*inv; o.y = ay*inv;
  ((float2*)agg)[(size_t)n*64 + lane] = o;
}

// ---- fused gated-MLP: 128 nodes/block, 8 waves, bf16 MFMA 16x16x32 ----

__global__ __launch_bounds__(512) void mlp_kernel(const float* __restrict__ agg,
    const float* __restrict__ Win, const float* __restrict__ bin,
    const float* __restrict__ Wg,  const float* __restrict__ bg,
    const float* __restrict__ Wo,  const float* __restrict__ bo,
    float* __restrict__ out, int N){
  __shared__ unsigned short s_wa[HID*LDW];   // W_in, then W_out (bf16, row-major [k][d])
  __shared__ unsigned short s_wb[HID*LDW];   // W_gate
  __shared__ unsigned short s_ag[HID*LDW];   // agg tile [node][d], later t tile [node][k]
  __shared__ float s_bias[3*HID];
  const int tid = threadIdx.x;
  const int n0 = blockIdx.x * 128;

  if (tid < 3*HID){
    const float* bsrc = (tid < HID) ? bin : ((tid < 2*HID) ? bg : bo);
    s_bias[tid] = bsrc[tid & (HID-1)];
  }
  // stage W_in + W_gate as bf16
  for (int idx = tid; idx < HID*32; idx += 512){
    int k = idx >> 5, c4 = (idx & 31) << 2;
    float4 wi = *(const float4*)(Win + k*HID + c4);
    float4 wg = *(const float4*)(Wg  + k*HID + c4);
    us4 ui = { f2bf(wi.x), f2bf(wi.y), f2bf(wi.z), f2bf(wi.w) };
    us4 ug = { f2bf(wg.x), f2bf(wg.y), f2bf(wg.z), f2bf(wg.w) };
    *(us4*)(&s_wa[k*LDW + c4]) = ui;
    *(us4*)(&s_wb[k*LDW + c4]) = ug;
  }
  // stage agg tile as bf16 (clamp row for the partial last block)
  for (int idx = tid; idx < 128*32; idx += 512){
    int r = idx >> 5, c4 = (idx & 31) << 2;
    int nn = n0 + r; if (nn > N-1) nn = N-1;
    float4 a = *(const float4*)(agg + (size_t)nn*HID + c4);
    us4 ua = { f2bf(a.x), f2bf(a.y), f2bf(a.z), f2bf(a.w) };
    *(us4*)(&s_ag[r*LDW + c4]) = ua;
  }
  __syncthreads();

  const int l  = tid & 63;
  const int wv = tid >> 6;
  const int r0 = wv * 16;              // this wave's 16 nodes within tile
  const int arow = r0 + (l & 15);      // A-frag row (node)
  const int kq = (l >> 4) * 8;         // A/B frag k sub-offset

  bf16x8 afr[4];
  #pragma unroll
  for (int ks = 0; ks < 4; ++ks)
    afr[ks] = *(const bf16x8*)(&s_ag[arow*LDW + ks*32 + kq]);

  f32x4 acch[8], accg[8];
  #pragma unroll
  for (int nf = 0; nf < 8; ++nf){ acch[nf] = {0.f,0.f,0.f,0.f}; accg[nf] = {0.f,0.f,0.f,0.f}; }

  #pragma unroll
  for (int nf = 0; nf < 8; ++nf){
    const int wbase = (nf*16 + (l & 15))*LDW;   // B col = W row (h/g output dim)
    #pragma unroll
    for (int ks = 0; ks < 4; ++ks){
      bf16x8 b1 = *(const bf16x8*)(&s_wa[wbase + ks*32 + kq]);
      bf16x8 b2 = *(const bf16x8*)(&s_wb[wbase + ks*32 + kq]);
      acch[nf] = __builtin_amdgcn_mfma_f32_16x16x32_bf16(afr[ks], b1, acch[nf], 0, 0, 0);
      accg[nf] = __builtin_amdgcn_mfma_f32_16x16x32_bf16(afr[ks], b2, accg[nf], 0, 0, 0);
    }
  }

  // epilogue 1: t = relu(h)*sigmoid(g) -> bf16 into s_ag (own wave's rows only)
  const int rb = r0 + (l >> 4) * 4;
  #pragma unroll
  for (int nf = 0; nf < 8; ++nf){
    const int c = nf*16 + (l & 15);
    const float bi = s_bias[c], bgv = s_bias[HID + c];
    #pragma unroll
    for (int rg = 0; rg < 4; ++rg){
      float h = acch[nf][rg] + bi;
      float g = accg[nf][rg] + bgv;
      float t = fmaxf(h, 0.f) * (1.f / (1.f + __expf(-g)));
      s_ag[(rb + rg)*LDW + c] = f2bf(t);
    }
  }
  __syncthreads();
  // stage W_out over W_in's slot
  for (int idx = tid; idx < HID*32; idx += 512){
    int k = idx >> 5, c4 = (idx & 31) << 2;
    float4 wo = *(const float4*)(Wo + k*HID + c4);
    us4 uo = { f2bf(wo.x), f2bf(wo.y), f2bf(wo.z), f2bf(wo.w) };
    *(us4*)(&s_wa[k*LDW + c4]) = uo;
  }
  __syncthreads();

  bf16x8 tfr[4];
  #pragma unroll
  for (int ks = 0; ks < 4; ++ks)
    tfr[ks] = *(const bf16x8*)(&s_ag[arow*LDW + ks*32 + kq]);

  f32x4 acco[8];
  #pragma unroll
  for (int nf = 0; nf < 8; ++nf) acco[nf] = {0.f,0.f,0.f,0.f};
  #pragma unroll
  for (int nf = 0; nf < 8; ++nf){
    const int wbase = (nf*16 + (l & 15))*LDW;
    #pragma unroll
    for (int ks = 0; ks < 4; ++ks){
      bf16x8 b3 = *(const bf16x8*)(&s_wa[wbase + ks*32 + kq]);
      acco[nf] = __builtin_amdgcn_mfma_f32_16x16x32_bf16(tfr[ks], b3, acco[nf], 0, 0, 0);
    }
  }
  #pragma unroll
  for (int nf = 0; nf < 8; ++nf){
    const int c = nf*16 + (l & 15);
    const float bov = s_bias[2*HID + c];
    #pragma unroll
    for (int rg = 0; rg < 4; ++rg){
      int node = n0 + rb + rg;
      if (node < N) out[(size_t)node*HID + c] = acco[nf][rg] + bov;
    }
  }
}

extern "C" void kernel_launch(void* const* d_in, const int* in_sizes, int n_in,
                              void* d_out, int out_size, void* d_ws, size_t ws_size,
                              hipStream_t stream){
  const float* X   = (const float*)d_in[0];
  const int*   ei  = (const int*)d_in[1];
  const float* Win = (const float*)d_in[2];
  const float* bin = (const float*)d_in[3];
  const float* Wg  = (const float*)d_in[4];
  const float* bg  = (const float*)d_in[5];
  const float* Wo  = (const float*)d_in[6];
  const float* bo  = (const float*)d_in[7];
  float* out = (float*)d_out;
  const int N = in_sizes[0] / HID;   // 100000
  const int E = in_sizes[1] / 2;     // 640000

  char* ws   = (char*)d_ws;
  float* agg = (float*)ws;                               // N*HID f32
  int* cnt   = (int*)(ws + (size_t)N*HID*sizeof(float)); // N
  int* cur   = cnt + N;                                  // N
  int* gcur  = cur + N;                                  // 1
  int* off   = gcur + 1;                                 // N
  int* elist = off + N;                                  // E

  hipMemsetAsync(cnt, 0, (size_t)(2*N + 1)*sizeof(int), stream);
  count_kernel  <<<(E + 255)/256, 256, 0, stream>>>(ei, cnt, E);
  offsets_kernel<<<(N + 255)/256, 256, 0, stream>>>(cnt, off, gcur, N);
  fill_kernel   <<<(E + 255)/256, 256, 0, stream>>>(ei, off, cur, elist, E);
  gather_kernel <<<(N + 3)/4,     256, 0, stream>>>(X, elist, off, cnt, agg, N);
  mlp_kernel    <<<(N + 127)/128, 512, 0, stream>>>(agg, Win, bin, Wg, bg, Wo, bo, out, N);
}

// Round 2
// 199.110 us; speedup vs baseline: 1.1566x; 1.1566x over previous
//
#include <hip/hip_runtime.h>
#include <hip/hip_bf16.h>

#define HID 128
#define LDW 136   // padded LDS row stride (bf16 elems)

typedef __attribute__((ext_vector_type(8))) __bf16 bf16x8;
typedef __attribute__((ext_vector_type(4))) float f32x4;
typedef __attribute__((ext_vector_type(4))) unsigned short us4;
typedef __attribute__((ext_vector_type(8))) unsigned short us8;

__device__ __forceinline__ unsigned short f2bf(float f){
  unsigned int u = __float_as_uint(f);
  unsigned int r = (u + 0x7FFFu + ((u >> 16) & 1u)) >> 16;  // RNE
  return (unsigned short)r;
}

// ---- X -> bf16 (packed pairs) ----
__global__ void conv_kernel(const float* __restrict__ X, uint2* __restrict__ Xb, int n4){
  int i = blockIdx.x*256 + threadIdx.x;
  if (i >= n4) return;
  float4 v = ((const float4*)X)[i];
  uint2 o;
  o.x = (unsigned)f2bf(v.x) | ((unsigned)f2bf(v.y) << 16);
  o.y = (unsigned)f2bf(v.z) | ((unsigned)f2bf(v.w) << 16);
  Xb[i] = o;
}

// ---- build per-dst CSR (no fp32 atomics) ----
__global__ void count_kernel(const int* __restrict__ ei, int* __restrict__ cnt, int E){
  int e = blockIdx.x*256 + threadIdx.x;
  if (e < E) atomicAdd(&cnt[ei[E + e]], 1);
}

__global__ void offsets_kernel(const int* __restrict__ cnt, int* __restrict__ off,
                               int* __restrict__ gcur, int N){
  int n = blockIdx.x*256 + threadIdx.x;
  int lane = threadIdx.x & 63;
  int c = (n < N) ? cnt[n] : 0;
  int incl = c;
  #pragma unroll
  for (int s = 1; s < 64; s <<= 1){
    int u = __shfl_up(incl, s);
    if (lane >= s) incl += u;
  }
  int total = __shfl(incl, 63);
  int base = 0;
  if (lane == 63) base = atomicAdd(gcur, total);
  base = __shfl(base, 63);
  if (n < N) off[n] = base + incl - c;
}

// post-increments off[d]; afterwards off[n] == segment END (start = off[n]-cnt[n])
__global__ void fill_kernel(const int* __restrict__ ei, int* __restrict__ off,
                            int* __restrict__ elist, int E){
  int e = blockIdx.x*256 + threadIdx.x;
  if (e >= E) return;
  int s = ei[e], d = ei[E + e];
  int slot = atomicAdd(&off[d], 1);
  elist[slot] = s;
}

// one wave per node: preload edge srcs into lanes, shfl-broadcast, 4-deep unroll
__global__ __launch_bounds__(512) void gather_kernel(const unsigned int* __restrict__ Xp,
                              const int* __restrict__ elist,
                              const int* __restrict__ off, const int* __restrict__ cnt,
                              unsigned int* __restrict__ agg, int N){
  int wv = threadIdx.x >> 6, lane = threadIdx.x & 63;
  int n = blockIdx.x*8 + wv;
  if (n >= N) return;
  int d = cnt[n];
  int base = off[n] - d;           // off was post-incremented to segment end
  float ax = 0.f, ay = 0.f;
  for (int c0 = 0; c0 < d; c0 += 64){
    int rem = d - c0; if (rem > 64) rem = 64;
    int sp = (lane < rem) ? elist[base + c0 + lane] : 0;
    int j = 0;
    for (; j + 4 <= rem; j += 4){
      int s0 = __shfl(sp, j),   s1 = __shfl(sp, j+1);
      int s2 = __shfl(sp, j+2), s3 = __shfl(sp, j+3);
      unsigned int p0 = Xp[(size_t)s0*64 + lane];
      unsigned int p1 = Xp[(size_t)s1*64 + lane];
      unsigned int p2 = Xp[(size_t)s2*64 + lane];
      unsigned int p3 = Xp[(size_t)s3*64 + lane];
      ax += __uint_as_float(p0 << 16) + __uint_as_float(p1 << 16)
          + __uint_as_float(p2 << 16) + __uint_as_float(p3 << 16);
      ay += __uint_as_float(p0 & 0xFFFF0000u) + __uint_as_float(p1 & 0xFFFF0000u)
          + __uint_as_float(p2 & 0xFFFF0000u) + __uint_as_float(p3 & 0xFFFF0000u);
    }
    for (; j < rem; ++j){
      int s0 = __shfl(sp, j);
      unsigned int p0 = Xp[(size_t)s0*64 + lane];
      ax += __uint_as_float(p0 << 16);
      ay += __uint_as_float(p0 & 0xFFFF0000u);
    }
  }
  float inv = (d > 0) ? 1.f/(float)d : 0.f;
  unsigned int r = (unsigned int)f2bf(ax*inv) | ((unsigned int)f2bf(ay*inv) << 16);
  agg[(size_t)n*64 + lane] = r;
}

// ---- fused gated-MLP: 128 nodes/block, 8 waves, bf16 MFMA 16x16x32 ----
__global__ __launch_bounds__(512) void mlp_kernel(const unsigned short* __restrict__ aggb,
    const float* __restrict__ Win, const float* __restrict__ bin,
    const float* __restrict__ Wg,  const float* __restrict__ bg,
    const float* __restrict__ Wo,  const float* __restrict__ bo,
    float* __restrict__ out, int N){
  __shared__ unsigned short s_wa[HID*LDW];   // W_in, then W_out
  __shared__ unsigned short s_wb[HID*LDW];   // W_gate
  __shared__ unsigned short s_ag[HID*LDW];   // agg tile, later t tile
  __shared__ float s_bias[3*HID];
  const int tid = threadIdx.x;
  const int n0 = blockIdx.x * 128;

  if (tid < 3*HID){
    const float* bsrc = (tid < HID) ? bin : ((tid < 2*HID) ? bg : bo);
    s_bias[tid] = bsrc[tid & (HID-1)];
  }
  for (int idx = tid; idx < HID*32; idx += 512){
    int k = idx >> 5, c4 = (idx & 31) << 2;
    float4 wi = *(const float4*)(Win + k*HID + c4);
    float4 wg = *(const float4*)(Wg  + k*HID + c4);
    us4 ui = { f2bf(wi.x), f2bf(wi.y), f2bf(wi.z), f2bf(wi.w) };
    us4 ug = { f2bf(wg.x), f2bf(wg.y), f2bf(wg.z), f2bf(wg.w) };
    *(us4*)(&s_wa[k*LDW + c4]) = ui;
    *(us4*)(&s_wb[k*LDW + c4]) = ug;
  }
  // stage agg tile (already bf16): 16B per op
  for (int idx = tid; idx < 128*16; idx += 512){
    int r = idx >> 4, c8 = (idx & 15) << 3;
    int nn = n0 + r; if (nn > N-1) nn = N-1;
    *(us8*)(&s_ag[r*LDW + c8]) = *(const us8*)(aggb + (size_t)nn*HID + c8);
  }
  __syncthreads();

  const int l  = tid & 63;
  const int wv = tid >> 6;
  const int r0 = wv * 16;
  const int arow = r0 + (l & 15);
  const int kq = (l >> 4) * 8;

  bf16x8 afr[4];
  #pragma unroll
  for (int ks = 0; ks < 4; ++ks)
    afr[ks] = *(const bf16x8*)(&s_ag[arow*LDW + ks*32 + kq]);

  f32x4 acch[8], accg[8];
  #pragma unroll
  for (int nf = 0; nf < 8; ++nf){ acch[nf] = {0.f,0.f,0.f,0.f}; accg[nf] = {0.f,0.f,0.f,0.f}; }

  #pragma unroll
  for (int nf = 0; nf < 8; ++nf){
    const int wbase = (nf*16 + (l & 15))*LDW;
    #pragma unroll
    for (int ks = 0; ks < 4; ++ks){
      bf16x8 b1 = *(const bf16x8*)(&s_wa[wbase + ks*32 + kq]);
      bf16x8 b2 = *(const bf16x8*)(&s_wb[wbase + ks*32 + kq]);
      acch[nf] = __builtin_amdgcn_mfma_f32_16x16x32_bf16(afr[ks], b1, acch[nf], 0, 0, 0);
      accg[nf] = __builtin_amdgcn_mfma_f32_16x16x32_bf16(afr[ks], b2, accg[nf], 0, 0, 0);
    }
  }

  const int rb = r0 + (l >> 4) * 4;
  #pragma unroll
  for (int nf = 0; nf < 8; ++nf){
    const int c = nf*16 + (l & 15);
    const float bi = s_bias[c], bgv = s_bias[HID + c];
    #pragma unroll
    for (int rg = 0; rg < 4; ++rg){
      float h = acch[nf][rg] + bi;
      float g = accg[nf][rg] + bgv;
      float t = fmaxf(h, 0.f) * (1.f / (1.f + __expf(-g)));
      s_ag[(rb + rg)*LDW + c] = f2bf(t);
    }
  }
  __syncthreads();
  for (int idx = tid; idx < HID*32; idx += 512){
    int k = idx >> 5, c4 = (idx & 31) << 2;
    float4 wo = *(const float4*)(Wo + k*HID + c4);
    us4 uo = { f2bf(wo.x), f2bf(wo.y), f2bf(wo.z), f2bf(wo.w) };
    *(us4*)(&s_wa[k*LDW + c4]) = uo;
  }
  __syncthreads();

  bf16x8 tfr[4];
  #pragma unroll
  for (int ks = 0; ks < 4; ++ks)
    tfr[ks] = *(const bf16x8*)(&s_ag[arow*LDW + ks*32 + kq]);

  f32x4 acco[8];
  #pragma unroll
  for (int nf = 0; nf < 8; ++nf) acco[nf] = {0.f,0.f,0.f,0.f};
  #pragma unroll
  for (int nf = 0; nf < 8; ++nf){
    const int wbase = (nf*16 + (l & 15))*LDW;
    #pragma unroll
    for (int ks = 0; ks < 4; ++ks){
      bf16x8 b3 = *(const bf16x8*)(&s_wa[wbase + ks*32 + kq]);
      acco[nf] = __builtin_amdgcn_mfma_f32_16x16x32_bf16(tfr[ks], b3, acco[nf], 0, 0, 0);
    }
  }
  #pragma unroll
  for (int nf = 0; nf < 8; ++nf){
    const int c = nf*16 + (l & 15);
    const float bov = s_bias[2*HID + c];
    #pragma unroll
    for (int rg = 0; rg < 4; ++rg){
      int node = n0 + rb + rg;
      if (node < N) out[(size_t)node*HID + c] = acco[nf][rg] + bov;
    }
  }
}

extern "C" void kernel_launch(void* const* d_in, const int* in_sizes, int n_in,
                              void* d_out, int out_size, void* d_ws, size_t ws_size,
                              hipStream_t stream){
  const float* X   = (const float*)d_in[0];
  const int*   ei  = (const int*)d_in[1];
  const float* Win = (const float*)d_in[2];
  const float* bin = (const float*)d_in[3];
  const float* Wg  = (const float*)d_in[4];
  const float* bg  = (const float*)d_in[5];
  const float* Wo  = (const float*)d_in[6];
  const float* bo  = (const float*)d_in[7];
  float* out = (float*)d_out;
  const int N = in_sizes[0] / HID;   // 100000
  const int E = in_sizes[1] / 2;     // 640000

  char* ws = (char*)d_ws;
  unsigned int*   Xb  = (unsigned int*)ws;                     // N*64 uints (bf16x2)
  unsigned short* agg = (unsigned short*)(ws + (size_t)N*HID*2); // N*HID bf16
  int* cnt   = (int*)(ws + (size_t)2*N*HID*2);                 // N
  int* gcur  = cnt + N;                                        // 1
  int* off   = gcur + 1;                                       // N
  int* elist = off + N;                                        // E

  hipMemsetAsync(cnt, 0, (size_t)(N + 1)*sizeof(int), stream);
  conv_kernel   <<<(N*HID/4 + 255)/256, 256, 0, stream>>>(X, (uint2*)Xb, N*HID/4);
  count_kernel  <<<(E + 255)/256, 256, 0, stream>>>(ei, cnt, E);
  offsets_kernel<<<(N + 255)/256, 256, 0, stream>>>(cnt, off, gcur, N);
  fill_kernel   <<<(E + 255)/256, 256, 0, stream>>>(ei, off, elist, E);
  gather_kernel <<<(N + 7)/8,     512, 0, stream>>>(Xb, elist, off, cnt, (unsigned int*)agg, N);
  mlp_kernel    <<<(N + 127)/128, 512, 0, stream>>>(agg, Win, bin, Wg, bg, Wo, bo, out, N);
}

// Round 3
// 192.960 us; speedup vs baseline: 1.1935x; 1.0319x over previous
//
#include <hip/hip_runtime.h>
#include <hip/hip_bf16.h>

#define HID 128

typedef __attribute__((ext_vector_type(8))) __bf16 bf16x8;
typedef __attribute__((ext_vector_type(4))) float f32x4;
typedef __attribute__((ext_vector_type(8))) unsigned short us8;

__device__ __forceinline__ unsigned short f2bf(float f){
  unsigned int u = __float_as_uint(f);
  unsigned int r = (u + 0x7FFFu + ((u >> 16) & 1u)) >> 16;  // RNE
  return (unsigned short)r;
}

// ---- X -> bf16 (packed pairs) ----
__global__ void conv_kernel(const float* __restrict__ X, uint2* __restrict__ Xb, int n4){
  int i = blockIdx.x*256 + threadIdx.x;
  if (i >= n4) return;
  float4 v = ((const float4*)X)[i];
  uint2 o;
  o.x = (unsigned)f2bf(v.x) | ((unsigned)f2bf(v.y) << 16);
  o.y = (unsigned)f2bf(v.z) | ((unsigned)f2bf(v.w) << 16);
  Xb[i] = o;
}

// ---- weights -> fragment-ordered bf16: Wfrag[m][nf][ks][l][e] = W_m[nf*16+(l&15)][ks*32+(l>>4)*8+e]
__global__ void wprep_kernel(const float* __restrict__ Win, const float* __restrict__ Wg,
                             const float* __restrict__ Wo, unsigned short* __restrict__ wfrag){
  int f = blockIdx.x*256 + threadIdx.x;       // 3*2048 fragments
  if (f >= 3*2048) return;
  int m = f >> 11, fi = f & 2047;
  int l = fi & 63, nfks = fi >> 6, ks = nfks & 3, nf = nfks >> 2;
  const float* W = (m == 0) ? Win : ((m == 1) ? Wg : Wo);
  int row = nf*16 + (l & 15), k0 = ks*32 + ((l >> 4) << 3);
  float4 a = *(const float4*)(W + row*HID + k0);
  float4 b = *(const float4*)(W + row*HID + k0 + 4);
  us8 o = { f2bf(a.x), f2bf(a.y), f2bf(a.z), f2bf(a.w),
            f2bf(b.x), f2bf(b.y), f2bf(b.z), f2bf(b.w) };
  *(us8*)(wfrag + (size_t)f*8) = o;
}

// ---- build per-dst CSR ----
__global__ void count_kernel(const int* __restrict__ ei, int* __restrict__ cnt, int E){
  int e = blockIdx.x*256 + threadIdx.x;
  if (e < E) atomicAdd(&cnt[ei[E + e]], 1);
}

__global__ void offsets_kernel(const int* __restrict__ cnt, int* __restrict__ off,
                               int* __restrict__ gcur, int N){
  int n = blockIdx.x*256 + threadIdx.x;
  int lane = threadIdx.x & 63;
  int c = (n < N) ? cnt[n] : 0;
  int incl = c;
  #pragma unroll
  for (int s = 1; s < 64; s <<= 1){
    int u = __shfl_up(incl, s);
    if (lane >= s) incl += u;
  }
  int total = __shfl(incl, 63);
  int base = 0;
  if (lane == 63) base = atomicAdd(gcur, total);
  base = __shfl(base, 63);
  if (n < N) off[n] = base + incl - c;
}

// post-increments off[d]; afterwards off[n] == segment END
__global__ void fill_kernel(const int* __restrict__ ei, int* __restrict__ off,
                            int* __restrict__ elist, int E){
  int e = blockIdx.x*256 + threadIdx.x;
  if (e >= E) return;
  int s = ei[e], d = ei[E + e];
  int slot = atomicAdd(&off[d], 1);
  elist[slot] = s;
}

// one wave per node, 2 edges per load-instruction (uint2/lane, 32 lanes/row),
// 2-stage software pipeline: ~8 rows in flight, masked adds for tails
__global__ __launch_bounds__(512) void gather_kernel(const uint2* __restrict__ X2,
                              const int* __restrict__ elist,
                              const int* __restrict__ off, const int* __restrict__ cnt,
                              uint2* __restrict__ agg2, int N){
  int wv = threadIdx.x >> 6, lane = threadIdx.x & 63;
  int n = blockIdx.x*8 + wv;
  if (n >= N) return;
  int d = cnt[n];
  int base = off[n] - d;
  int h = lane >> 5;          // edge parity within slot pair
  int cl = lane & 31;         // column-quad index
  float a0=0.f, a1=0.f, a2=0.f, a3=0.f;
  for (int c0 = 0; c0 < d; c0 += 64){
    int rem = d - c0; if (rem > 64) rem = 64;
    int m = rem - 1;
    int sp = (lane < rem) ? elist[base + c0 + lane] : 0;
    uint2 p[4];
    #pragma unroll
    for (int u = 0; u < 4; ++u){
      int e = 2*u + h; if (e > m) e = m;
      int s = __shfl(sp, e);
      p[u] = X2[(size_t)s*32 + cl];
    }
    for (int j = 0; j < rem; j += 8){
      uint2 q[4];
      bool more = (j + 8) < rem;
      if (more){
        #pragma unroll
        for (int u = 0; u < 4; ++u){
          int e = j + 8 + 2*u + h; if (e > m) e = m;
          int s = __shfl(sp, e);
          q[u] = X2[(size_t)s*32 + cl];
        }
      }
      #pragma unroll
      for (int u = 0; u < 4; ++u){
        int e = j + 2*u + h;
        float msk = (e <= m) ? 1.f : 0.f;
        a0 += msk * __uint_as_float(p[u].x << 16);
        a1 += msk * __uint_as_float(p[u].x & 0xFFFF0000u);
        a2 += msk * __uint_as_float(p[u].y << 16);
        a3 += msk * __uint_as_float(p[u].y & 0xFFFF0000u);
      }
      if (more){
        #pragma unroll
        for (int u = 0; u < 4; ++u) p[u] = q[u];
      }
    }
  }
  a0 += __shfl_xor(a0, 32); a1 += __shfl_xor(a1, 32);
  a2 += __shfl_xor(a2, 32); a3 += __shfl_xor(a3, 32);
  if (lane < 32){
    float inv = (d > 0) ? 1.f/(float)d : 0.f;
    uint2 o;
    o.x = (unsigned)f2bf(a0*inv) | ((unsigned)f2bf(a1*inv) << 16);
    o.y = (unsigned)f2bf(a2*inv) | ((unsigned)f2bf(a3*inv) << 16);
    agg2[(size_t)n*32 + cl] = o;
  }
}

// ---- fused gated-MLP: 128 nodes/block, 8 waves; fragment-ordered bf16 weights in LDS,
//      A-frags direct from global, per-wave t-scratch, ONE barrier total ----
__global__ __launch_bounds__(512) void mlp_kernel(const unsigned short* __restrict__ aggb,
    const unsigned short* __restrict__ wfrag,
    const float* __restrict__ bin, const float* __restrict__ bg, const float* __restrict__ bo,
    float* __restrict__ out, int N){
  __shared__ unsigned short s_w[3*16384];   // Win | Wg | Wo, fragment order (96 KB)
  __shared__ unsigned short s_t[8*2048];    // per-wave t scratch (32 KB)
  __shared__ float s_bias[3*HID];
  const int tid = threadIdx.x;
  const int n0 = blockIdx.x * 128;

  for (int i = tid; i < 6144; i += 512)
    ((us8*)s_w)[i] = ((const us8*)wfrag)[i];
  if (tid < 3*HID){
    const float* bsrc = (tid < HID) ? bin : ((tid < 2*HID) ? bg : bo);
    s_bias[tid] = bsrc[tid & (HID-1)];
  }
  __syncthreads();

  const int l  = tid & 63;
  const int wv = tid >> 6;
  const int r0 = wv * 16;
  const int kq = (l >> 4) * 8;

  int arow = n0 + r0 + (l & 15); if (arow > N-1) arow = N-1;
  bf16x8 afr[4];
  #pragma unroll
  for (int ks = 0; ks < 4; ++ks)
    afr[ks] = *(const bf16x8*)(aggb + (size_t)arow*HID + ks*32 + kq);

  f32x4 acch[8], accg[8];
  #pragma unroll
  for (int nf = 0; nf < 8; ++nf){ acch[nf] = {0.f,0.f,0.f,0.f}; accg[nf] = {0.f,0.f,0.f,0.f}; }

  #pragma unroll
  for (int nf = 0; nf < 8; ++nf){
    #pragma unroll
    for (int ks = 0; ks < 4; ++ks){
      const int fb = ((nf*4 + ks)*64 + l) * 8;
      bf16x8 b1 = *(const bf16x8*)(s_w + fb);            // W_in
      bf16x8 b2 = *(const bf16x8*)(s_w + 16384 + fb);    // W_gate
      acch[nf] = __builtin_amdgcn_mfma_f32_16x16x32_bf16(afr[ks], b1, acch[nf], 0, 0, 0);
      accg[nf] = __builtin_amdgcn_mfma_f32_16x16x32_bf16(afr[ks], b2, accg[nf], 0, 0, 0);
    }
  }

  // epilogue 1: t = relu(h)*sigmoid(g) -> per-wave fragment-ordered scratch (XOR-swizzled)
  unsigned short* tw = s_t + wv*2048;
  const int rrb = (l >> 4) * 4;
  #pragma unroll
  for (int nf = 0; nf < 8; ++nf){
    const int c = nf*16 + (l & 15);
    const int ks2 = c >> 5, sub = (c >> 3) & 3, e = c & 7;
    const float bi = s_bias[c], bgv = s_bias[HID + c];
    #pragma unroll
    for (int rg = 0; rg < 4; ++rg){
      float hh = acch[nf][rg] + bi;
      float gg = accg[nf][rg] + bgv;
      float t = fmaxf(hh, 0.f) * (1.f / (1.f + __expf(-gg)));
      int blk = sub*16 + rrb + rg;
      blk ^= (blk >> 4) & 3;
      tw[ks2*512 + blk*8 + e] = f2bf(t);
    }
  }
  // same-wave LDS write->read: no __syncthreads needed (compiler inserts lgkmcnt wait)

  bf16x8 tfr[4];
  #pragma unroll
  for (int ks = 0; ks < 4; ++ks)
    tfr[ks] = *(const bf16x8*)(tw + ks*512 + (size_t)(l ^ ((l >> 4) & 3))*8);

  f32x4 acco[8];
  #pragma unroll
  for (int nf = 0; nf < 8; ++nf) acco[nf] = {0.f,0.f,0.f,0.f};
  #pragma unroll
  for (int nf = 0; nf < 8; ++nf){
    #pragma unroll
    for (int ks = 0; ks < 4; ++ks){
      const int fb = ((nf*4 + ks)*64 + l) * 8;
      bf16x8 b3 = *(const bf16x8*)(s_w + 32768 + fb);    // W_out
      acco[nf] = __builtin_amdgcn_mfma_f32_16x16x32_bf16(tfr[ks], b3, acco[nf], 0, 0, 0);
    }
  }
  #pragma unroll
  for (int nf = 0; nf < 8; ++nf){
    const int c = nf*16 + (l & 15);
    const float bov = s_bias[2*HID + c];
    #pragma unroll
    for (int rg = 0; rg < 4; ++rg){
      int node = n0 + r0 + rrb + rg;
      if (node < N) out[(size_t)node*HID + c] = acco[nf][rg] + bov;
    }
  }
}

extern "C" void kernel_launch(void* const* d_in, const int* in_sizes, int n_in,
                              void* d_out, int out_size, void* d_ws, size_t ws_size,
                              hipStream_t stream){
  const float* X   = (const float*)d_in[0];
  const int*   ei  = (const int*)d_in[1];
  const float* Win = (const float*)d_in[2];
  const float* bin = (const float*)d_in[3];
  const float* Wg  = (const float*)d_in[4];
  const float* bg  = (const float*)d_in[5];
  const float* Wo  = (const float*)d_in[6];
  const float* bo  = (const float*)d_in[7];
  float* out = (float*)d_out;
  const int N = in_sizes[0] / HID;   // 100000
  const int E = in_sizes[1] / 2;     // 640000

  unsigned short* Xb    = (unsigned short*)d_ws;         // N*HID bf16
  unsigned short* agg   = Xb + (size_t)N*HID;            // N*HID bf16
  unsigned short* wfrag = agg + (size_t)N*HID;           // 3*16384 bf16
  int* cnt   = (int*)(wfrag + 3*16384);                  // N
  int* gcur  = cnt + N;                                  // 1
  int* off   = gcur + 1;                                 // N
  int* elist = off + N;                                  // E

  hipMemsetAsync(cnt, 0, (size_t)(N + 1)*sizeof(int), stream);
  conv_kernel   <<<(N*HID/4 + 255)/256, 256, 0, stream>>>(X, (uint2*)Xb, N*HID/4);
  wprep_kernel  <<<24, 256, 0, stream>>>(Win, Wg, Wo, wfrag);
  count_kernel  <<<(E + 255)/256, 256, 0, stream>>>(ei, cnt, E);
  offsets_kernel<<<(N + 255)/256, 256, 0, stream>>>(cnt, off, gcur, N);
  fill_kernel   <<<(E + 255)/256, 256, 0, stream>>>(ei, off, elist, E);
  gather_kernel <<<(N + 7)/8, 512, 0, stream>>>((const uint2*)Xb, elist, off, cnt, (uint2*)agg, N);
  mlp_kernel    <<<(N + 127)/128, 512, 0, stream>>>(agg, wfrag, bin, bg, bo, out, N);
}

// Round 4
// 173.806 us; speedup vs baseline: 1.3250x; 1.1102x over previous
//
#include <hip/hip_runtime.h>
#include <hip/hip_bf16.h>

#define HID 128

typedef __attribute__((ext_vector_type(8))) __bf16 bf16x8;
typedef __attribute__((ext_vector_type(4))) float f32x4;
typedef __attribute__((ext_vector_type(8))) unsigned short us8;

__device__ __forceinline__ unsigned short f2bf(float f){
  unsigned int u = __float_as_uint(f);
  unsigned int r = (u + 0x7FFFu + ((u >> 16) & 1u)) >> 16;  // RNE
  return (unsigned short)r;
}

// ---- merged: X -> bf16 conversion + edge-dst counting ----
__global__ void prep_kernel(const float* __restrict__ X, uint2* __restrict__ Xb, int n4,
                            const int* __restrict__ ei, int* __restrict__ cnt, int E){
  int i = blockIdx.x*256 + threadIdx.x;
  if (i < n4){
    float4 v = ((const float4*)X)[i];
    uint2 o;
    o.x = (unsigned)f2bf(v.x) | ((unsigned)f2bf(v.y) << 16);
    o.y = (unsigned)f2bf(v.z) | ((unsigned)f2bf(v.w) << 16);
    Xb[i] = o;
  }
  if (i < E) atomicAdd(&cnt[ei[E + i]], 1);
}

// ---- weights -> fragment-ordered bf16: Wfrag[m][nf][ks][l][e] = W_m[nf*16+(l&15)][ks*32+(l>>4)*8+e]
__global__ void wprep_kernel(const float* __restrict__ Win, const float* __restrict__ Wg,
                             const float* __restrict__ Wo, unsigned short* __restrict__ wfrag){
  int f = blockIdx.x*256 + threadIdx.x;       // 3*2048 fragments
  if (f >= 3*2048) return;
  int m = f >> 11, fi = f & 2047;
  int l = fi & 63, nfks = fi >> 6, ks = nfks & 3, nf = nfks >> 2;
  const float* W = (m == 0) ? Win : ((m == 1) ? Wg : Wo);
  int row = nf*16 + (l & 15), k0 = ks*32 + ((l >> 4) << 3);
  float4 a = *(const float4*)(W + row*HID + k0);
  float4 b = *(const float4*)(W + row*HID + k0 + 4);
  us8 o = { f2bf(a.x), f2bf(a.y), f2bf(a.z), f2bf(a.w),
            f2bf(b.x), f2bf(b.y), f2bf(b.z), f2bf(b.w) };
  *(us8*)(wfrag + (size_t)f*8) = o;
}

__global__ void offsets_kernel(const int* __restrict__ cnt, int* __restrict__ off,
                               int* __restrict__ gcur, int N){
  int n = blockIdx.x*256 + threadIdx.x;
  int lane = threadIdx.x & 63;
  int c = (n < N) ? cnt[n] : 0;
  int incl = c;
  #pragma unroll
  for (int s = 1; s < 64; s <<= 1){
    int u = __shfl_up(incl, s);
    if (lane >= s) incl += u;
  }
  int total = __shfl(incl, 63);
  int base = 0;
  if (lane == 63) base = atomicAdd(gcur, total);
  base = __shfl(base, 63);
  if (n < N) off[n] = base + incl - c;
}

// post-increments off[d]; afterwards off[n] == segment END
__global__ void fill_kernel(const int* __restrict__ ei, int* __restrict__ off,
                            int* __restrict__ elist, int E){
  int e = blockIdx.x*256 + threadIdx.x;
  if (e >= E) return;
  int s = ei[e], d = ei[E + e];
  int slot = atomicAdd(&off[d], 1);
  elist[slot] = s;
}

// one wave per node, 2 edges per load-instruction, 2-stage software pipeline
__global__ __launch_bounds__(512) void gather_kernel(const uint2* __restrict__ X2,
                              const int* __restrict__ elist,
                              const int* __restrict__ off, const int* __restrict__ cnt,
                              uint2* __restrict__ agg2, int N){
  int wv = threadIdx.x >> 6, lane = threadIdx.x & 63;
  int n = blockIdx.x*8 + wv;
  if (n >= N) return;
  int d = cnt[n];
  int base = off[n] - d;
  int h = lane >> 5;
  int cl = lane & 31;
  float a0=0.f, a1=0.f, a2=0.f, a3=0.f;
  for (int c0 = 0; c0 < d; c0 += 64){
    int rem = d - c0; if (rem > 64) rem = 64;
    int m = rem - 1;
    int sp = (lane < rem) ? elist[base + c0 + lane] : 0;
    uint2 p[4];
    #pragma unroll
    for (int u = 0; u < 4; ++u){
      int e = 2*u + h; if (e > m) e = m;
      int s = __shfl(sp, e);
      p[u] = X2[(size_t)s*32 + cl];
    }
    for (int j = 0; j < rem; j += 8){
      uint2 q[4];
      bool more = (j + 8) < rem;
      if (more){
        #pragma unroll
        for (int u = 0; u < 4; ++u){
          int e = j + 8 + 2*u + h; if (e > m) e = m;
          int s = __shfl(sp, e);
          q[u] = X2[(size_t)s*32 + cl];
        }
      }
      #pragma unroll
      for (int u = 0; u < 4; ++u){
        int e = j + 2*u + h;
        float msk = (e <= m) ? 1.f : 0.f;
        a0 += msk * __uint_as_float(p[u].x << 16);
        a1 += msk * __uint_as_float(p[u].x & 0xFFFF0000u);
        a2 += msk * __uint_as_float(p[u].y << 16);
        a3 += msk * __uint_as_float(p[u].y & 0xFFFF0000u);
      }
      if (more){
        #pragma unroll
        for (int u = 0; u < 4; ++u) p[u] = q[u];
      }
    }
  }
  a0 += __shfl_xor(a0, 32); a1 += __shfl_xor(a1, 32);
  a2 += __shfl_xor(a2, 32); a3 += __shfl_xor(a3, 32);
  if (lane < 32){
    float inv = (d > 0) ? 1.f/(float)d : 0.f;
    uint2 o;
    o.x = (unsigned)f2bf(a0*inv) | ((unsigned)f2bf(a1*inv) << 16);
    o.y = (unsigned)f2bf(a2*inv) | ((unsigned)f2bf(a3*inv) << 16);
    agg2[(size_t)n*32 + cl] = o;
  }
}

// ---- fused gated-MLP: 128 nodes/block, 8 waves.
// LDS holds only Win|Wg (64KB); after layer-1 the Wg region is reused as per-wave
// t-scratch; W_out B-frags stream from global (L2-hot). 2 blocks/CU.
__global__ __launch_bounds__(512, 4) void mlp_kernel(const unsigned short* __restrict__ aggb,
    const unsigned short* __restrict__ wfrag,
    const float* __restrict__ bin, const float* __restrict__ bg, const float* __restrict__ bo,
    float* __restrict__ out, int N){
  __shared__ unsigned short s_w[2*16384];   // Win | Wg (Wg region reused as t) — 64 KB
  __shared__ float s_bias[3*HID];
  const int tid = threadIdx.x;
  const int n0 = blockIdx.x * 128;

  for (int i = tid; i < 4096; i += 512)
    ((us8*)s_w)[i] = ((const us8*)wfrag)[i];
  if (tid < 3*HID){
    const float* bsrc = (tid < HID) ? bin : ((tid < 2*HID) ? bg : bo);
    s_bias[tid] = bsrc[tid & (HID-1)];
  }
  __syncthreads();

  const int l  = tid & 63;
  const int wv = tid >> 6;
  const int r0 = wv * 16;
  const int kq = (l >> 4) * 8;

  int arow = n0 + r0 + (l & 15); if (arow > N-1) arow = N-1;
  bf16x8 afr[4];
  #pragma unroll
  for (int ks = 0; ks < 4; ++ks)
    afr[ks] = *(const bf16x8*)(aggb + (size_t)arow*HID + ks*32 + kq);

  f32x4 acch[8], accg[8];
  #pragma unroll
  for (int nf = 0; nf < 8; ++nf){ acch[nf] = {0.f,0.f,0.f,0.f}; accg[nf] = {0.f,0.f,0.f,0.f}; }

  #pragma unroll
  for (int nf = 0; nf < 8; ++nf){
    #pragma unroll
    for (int ks = 0; ks < 4; ++ks){
      const int fb = ((nf*4 + ks)*64 + l) * 8;
      bf16x8 b1 = *(const bf16x8*)(s_w + fb);            // W_in
      bf16x8 b2 = *(const bf16x8*)(s_w + 16384 + fb);    // W_gate
      acch[nf] = __builtin_amdgcn_mfma_f32_16x16x32_bf16(afr[ks], b1, acch[nf], 0, 0, 0);
      accg[nf] = __builtin_amdgcn_mfma_f32_16x16x32_bf16(afr[ks], b2, accg[nf], 0, 0, 0);
    }
  }

  __syncthreads();   // all waves done reading Wg; its region becomes t-scratch

  // epilogue 1: t = relu(h)*sigmoid(g) -> per-wave fragment-ordered scratch (XOR-swizzled)
  unsigned short* tw = s_w + 16384 + wv*2048;
  const int rrb = (l >> 4) * 4;
  #pragma unroll
  for (int nf = 0; nf < 8; ++nf){
    const int c = nf*16 + (l & 15);
    const int ks2 = c >> 5, sub = (c >> 3) & 3, e = c & 7;
    const float bi = s_bias[c], bgv = s_bias[HID + c];
    #pragma unroll
    for (int rg = 0; rg < 4; ++rg){
      float hh = acch[nf][rg] + bi;
      float gg = accg[nf][rg] + bgv;
      float t = fmaxf(hh, 0.f) * (1.f / (1.f + __expf(-gg)));
      int blk = sub*16 + rrb + rg;
      blk ^= (blk >> 4) & 3;
      tw[ks2*512 + blk*8 + e] = f2bf(t);
    }
  }
  // same-wave LDS write->read: lgkmcnt ordering, no barrier needed

  bf16x8 tfr[4];
  #pragma unroll
  for (int ks = 0; ks < 4; ++ks)
    tfr[ks] = *(const bf16x8*)(tw + ks*512 + (size_t)(l ^ ((l >> 4) & 3))*8);

  f32x4 acco[8];
  #pragma unroll
  for (int nf = 0; nf < 8; ++nf) acco[nf] = {0.f,0.f,0.f,0.f};
  #pragma unroll
  for (int nf = 0; nf < 8; ++nf){
    #pragma unroll
    for (int ks = 0; ks < 4; ++ks){
      const int fb = ((nf*4 + ks)*64 + l) * 8;
      bf16x8 b3 = *(const bf16x8*)(wfrag + 32768 + fb);  // W_out from global (L2-hot)
      acco[nf] = __builtin_amdgcn_mfma_f32_16x16x32_bf16(tfr[ks], b3, acco[nf], 0, 0, 0);
    }
  }
  #pragma unroll
  for (int nf = 0; nf < 8; ++nf){
    const int c = nf*16 + (l & 15);
    const float bov = s_bias[2*HID + c];
    #pragma unroll
    for (int rg = 0; rg < 4; ++rg){
      int node = n0 + r0 + rrb + rg;
      if (node < N) out[(size_t)node*HID + c] = acco[nf][rg] + bov;
    }
  }
}

extern "C" void kernel_launch(void* const* d_in, const int* in_sizes, int n_in,
                              void* d_out, int out_size, void* d_ws, size_t ws_size,
                              hipStream_t stream){
  const float* X   = (const float*)d_in[0];
  const int*   ei  = (const int*)d_in[1];
  const float* Win = (const float*)d_in[2];
  const float* bin = (const float*)d_in[3];
  const float* Wg  = (const float*)d_in[4];
  const float* bg  = (const float*)d_in[5];
  const float* Wo  = (const float*)d_in[6];
  const float* bo  = (const float*)d_in[7];
  float* out = (float*)d_out;
  const int N = in_sizes[0] / HID;   // 100000
  const int E = in_sizes[1] / 2;     // 640000

  unsigned short* Xb    = (unsigned short*)d_ws;         // N*HID bf16
  unsigned short* agg   = Xb + (size_t)N*HID;            // N*HID bf16
  unsigned short* wfrag = agg + (size_t)N*HID;           // 3*16384 bf16
  int* cnt   = (int*)(wfrag + 3*16384);                  // N
  int* gcur  = cnt + N;                                  // 1
  int* off   = gcur + 1;                                 // N
  int* elist = off + N;                                  // E

  const int n4 = N*HID/4;
  hipMemsetAsync(cnt, 0, (size_t)(N + 1)*sizeof(int), stream);
  prep_kernel   <<<(n4 + 255)/256, 256, 0, stream>>>(X, (uint2*)Xb, n4, ei, cnt, E);
  wprep_kernel  <<<24, 256, 0, stream>>>(Win, Wg, Wo, wfrag);
  offsets_kernel<<<(N + 255)/256, 256, 0, stream>>>(cnt, off, gcur, N);
  fill_kernel   <<<(E + 255)/256, 256, 0, stream>>>(ei, off, elist, E);
  gather_kernel <<<(N + 7)/8, 512, 0, stream>>>((const uint2*)Xb, elist, off, cnt, (uint2*)agg, N);
  mlp_kernel    <<<(N + 127)/128, 512, 0, stream>>>(agg, wfrag, bin, bg, bo, out, N);
}